// Round 1
// 2708.462 us; speedup vs baseline: 3.3585x; 3.3585x over previous
//
#include <hip/hip_runtime.h>
#include <hip/hip_bf16.h>
#include <math.h>

// ---------------- problem constants ----------------
#define S 1024
#define H 2048
#define NH 16
#define HD 128
#define E 16
#define TOPK 4
#define IM 1408
#define IS 5632
#define EPS 1e-6f
#define THETA 1000000.0f

// =====================================================================
// MFMA bf16x3 GEMM machinery (f32 in/out, split-bf16 emulation)
//   C = A @ B,  A:[M,K] row-major, B:[K,N] row-major
//   A = Ah + Al (bf16 hi/lo), C ~= Ah*Bh + Ah*Bl + Al*Bh  (f32 MFMA accum)
// Tile: 64(M) x 128(N) x 32(K), 256 threads = 4 waves (2x2),
// per-wave 32x64 = 2x4 fragments of v_mfma_f32_16x16x32_bf16.
// =====================================================================
using bf16x8 = __attribute__((ext_vector_type(8))) __bf16;
using f32x4  = __attribute__((ext_vector_type(4))) float;

#define TBM 64
#define TBN 128
#define TBK 32
#define BKP 40            // padded k extent in bf16 elems (80B rows: 16B-aligned, de-power-of-2 banks)
#define MAX_TILES 80      // max sum_e ceil(cnt_e/64) = 4096/64 + 15 = 79

__device__ __forceinline__ void cvt8(const float* x, __bf16* h, __bf16* l) {
#pragma unroll
    for (int j = 0; j < 8; ++j) {
        __bf16 hj = (__bf16)x[j];
        h[j] = hj;
        l[j] = (__bf16)(x[j] - (float)hj);
    }
}

__device__ __forceinline__ void store8(__bf16* dst, const __bf16* v) {
    bf16x8 t;
#pragma unroll
    for (int j = 0; j < 8; ++j) t[j] = v[j];
    *reinterpret_cast<bf16x8*>(dst) = t;
}

// stage A tile (64 rows x 32 k) from dense rows. thread t: row t/4, k-quad t%4.
__device__ __forceinline__ void stage_A(const float* __restrict__ Atile, int lda, int t,
                                        __bf16 (*Ah)[BKP], __bf16 (*Al)[BKP]) {
    const int ar = t >> 2, kq = (t & 3) * 8;
    const float* p = Atile + (size_t)ar * lda + kq;
    float4 va = *(const float4*)p, vb = *(const float4*)(p + 4);
    float x[8] = {va.x, va.y, va.z, va.w, vb.x, vb.y, vb.z, vb.w};
    __bf16 hh[8], ll[8];
    cvt8(x, hh, ll);
    store8(&Ah[ar][kq], hh);
    store8(&Al[ar][kq], ll);
}

// stage B tile (32 k x 128 n) transposed into LDS [n][k].
// thread t: n-pair (t%64)*2, k-octet (t/64)*8. Loads are wave-coalesced (128
// consecutive floats per k-row across a wave).
__device__ __forceinline__ void stage_B(const float* __restrict__ Btile, int ldb, int t,
                                        __bf16 (*Bh)[BKP], __bf16 (*Bl)[BKP]) {
    const int n = (t & 63) * 2;
    const int kb = (t >> 6) * 8;
    const float* p = Btile + (size_t)kb * ldb + n;
    float xa[8], xb[8];
#pragma unroll
    for (int i = 0; i < 8; ++i) {
        float2 v = *(const float2*)(p + (size_t)i * ldb);
        xa[i] = v.x; xb[i] = v.y;
    }
    __bf16 hh[8], ll[8];
    cvt8(xa, hh, ll); store8(&Bh[n][kb], hh); store8(&Bl[n][kb], ll);
    cvt8(xb, hh, ll); store8(&Bh[n + 1][kb], hh); store8(&Bl[n + 1][kb], ll);
}

// one K-step of MFMA work for this thread's wave.
// A-frag: lane l -> row = l&15, k = (l>>4)*8.. ; B-frag: col = l&15, same k.
// D: col = lane&15, row = (lane>>4)*4 + reg   [HW-verified m89/m91]
__device__ __forceinline__ void compute_step(int lane, int wave,
        const __bf16 (*Ah)[BKP], const __bf16 (*Al)[BKP],
        const __bf16 (*Bh)[BKP], const __bf16 (*Bl)[BKP],
        f32x4 (&acc)[2][4]) {
    const int wr = (wave >> 1) * 32, wc = (wave & 1) * 64;
    const int lr = lane & 15, lk = (lane >> 4) * 8;
    bf16x8 ah[2], al[2], bh[4], bl[4];
#pragma unroll
    for (int fi = 0; fi < 2; ++fi) {
        ah[fi] = *reinterpret_cast<const bf16x8*>(&Ah[wr + fi * 16 + lr][lk]);
        al[fi] = *reinterpret_cast<const bf16x8*>(&Al[wr + fi * 16 + lr][lk]);
    }
#pragma unroll
    for (int fj = 0; fj < 4; ++fj) {
        bh[fj] = *reinterpret_cast<const bf16x8*>(&Bh[wc + fj * 16 + lr][lk]);
        bl[fj] = *reinterpret_cast<const bf16x8*>(&Bl[wc + fj * 16 + lr][lk]);
    }
#pragma unroll
    for (int fi = 0; fi < 2; ++fi)
#pragma unroll
        for (int fj = 0; fj < 4; ++fj) {
            acc[fi][fj] = __builtin_amdgcn_mfma_f32_16x16x32_bf16(ah[fi], bh[fj], acc[fi][fj], 0, 0, 0);
            acc[fi][fj] = __builtin_amdgcn_mfma_f32_16x16x32_bf16(ah[fi], bl[fj], acc[fi][fj], 0, 0, 0);
            acc[fi][fj] = __builtin_amdgcn_mfma_f32_16x16x32_bf16(al[fi], bh[fj], acc[fi][fj], 0, 0, 0);
        }
}

// dense body shared by mgemm / qkv kernels. M fixed = S (multiple of 64),
// N multiple of 128, K multiple of 32.
__device__ __forceinline__ void mgemm_body(const float* __restrict__ A, const float* __restrict__ B,
                                           const float* __restrict__ bias, const float* __restrict__ add,
                                           float* __restrict__ C, int N, int K, int m0, int n0) {
    __shared__ __align__(16) __bf16 Ah[TBM][BKP], Al[TBM][BKP], Bh[TBN][BKP], Bl[TBN][BKP];
    const int t = threadIdx.x, lane = t & 63, wave = t >> 6;
    f32x4 acc[2][4] = {};
    for (int k0 = 0; k0 < K; k0 += TBK) {
        stage_A(A + (size_t)m0 * K + k0, K, t, Ah, Al);
        stage_B(B + (size_t)k0 * N + n0, N, t, Bh, Bl);
        __syncthreads();
        compute_step(lane, wave, Ah, Al, Bh, Bl, acc);
        __syncthreads();
    }
    const int wr = (wave >> 1) * 32, wc = (wave & 1) * 64;
    const int lr = lane & 15, lg = (lane >> 4) * 4;
#pragma unroll
    for (int fi = 0; fi < 2; ++fi)
#pragma unroll
        for (int fj = 0; fj < 4; ++fj) {
            const int n = n0 + wc + fj * 16 + lr;
            const float bv = bias ? bias[n] : 0.f;
#pragma unroll
            for (int r = 0; r < 4; ++r) {
                const int m = m0 + wr + fi * 16 + lg + r;
                float val = acc[fi][fj][r] + bv;
                if (add) val += add[(size_t)m * N + n];
                C[(size_t)m * N + n] = val;
            }
        }
}

__global__ __launch_bounds__(256)
void mgemm_kernel(const float* __restrict__ A, const float* __restrict__ B,
                  const float* __restrict__ bias, const float* __restrict__ add,
                  float* __restrict__ C, int N, int K) {
    mgemm_body(A, B, bias, add, C, N, K, blockIdx.y * TBM, blockIdx.x * TBN);
}

// q,k,v fused into one launch: blockIdx.x in [0,48): which = x>>4, n-block = x&15
__global__ __launch_bounds__(256)
void mgemm_qkv_kernel(const float* __restrict__ Ain,
                      const float* __restrict__ qw, const float* __restrict__ kw,
                      const float* __restrict__ vw,
                      const float* __restrict__ qbias, const float* __restrict__ kbias,
                      const float* __restrict__ vbias,
                      float* __restrict__ qo, float* __restrict__ ko, float* __restrict__ vo) {
    const int which = blockIdx.x >> 4;
    const int n0 = (blockIdx.x & 15) * TBN;
    const float* B   = (which == 0) ? qw    : (which == 1) ? kw    : vw;
    const float* bia = (which == 0) ? qbias : (which == 1) ? kbias : vbias;
    float* C         = (which == 0) ? qo    : (which == 1) ? ko    : vo;
    mgemm_body(Ain, B, bia, nullptr, C, H, H, blockIdx.y * TBM, n0);
}

// grouped expert gate/up GEMM: rows gathered from h2 via tok_list.
// grid: (IM/TBN, MAX_TILES); tile -> (expert, m0) via device-built table.
__global__ __launch_bounds__(256)
void moe_gu_kernel(const float* __restrict__ h2, const float* __restrict__ Wall,
                   const int* __restrict__ counts, const int* __restrict__ offs,
                   const int* __restrict__ tok_list, const int* __restrict__ tile_e,
                   const int* __restrict__ tile_m0, const int* __restrict__ ntiles,
                   float* __restrict__ Cout) {
    const int tile = blockIdx.y;
    if (tile >= ntiles[0]) return;
    const int e = tile_e[tile], m0t = tile_m0[tile];
    const int base = offs[e], mleft = counts[e] - m0t;
    const float* B = Wall + (size_t)e * (size_t)H * IM;
    const int n0 = blockIdx.x * TBN;
    __shared__ __align__(16) __bf16 Ah[TBM][BKP], Al[TBM][BKP], Bh[TBN][BKP], Bl[TBN][BKP];
    __shared__ int toks[TBM];
    const int t = threadIdx.x, lane = t & 63, wave = t >> 6;
    if (t < TBM) toks[t] = (t < mleft) ? tok_list[base + m0t + t] : 0;
    __syncthreads();
    f32x4 acc[2][4] = {};
    const int ar = t >> 2, kq = (t & 3) * 8;
    for (int k0 = 0; k0 < H; k0 += TBK) {
        float x[8];
        if (ar < mleft) {
            const float* p = h2 + (size_t)toks[ar] * H + k0 + kq;
            float4 va = *(const float4*)p, vb = *(const float4*)(p + 4);
            x[0] = va.x; x[1] = va.y; x[2] = va.z; x[3] = va.w;
            x[4] = vb.x; x[5] = vb.y; x[6] = vb.z; x[7] = vb.w;
        } else {
#pragma unroll
            for (int j = 0; j < 8; ++j) x[j] = 0.f;
        }
        __bf16 hh[8], ll[8];
        cvt8(x, hh, ll);
        store8(&Ah[ar][kq], hh);
        store8(&Al[ar][kq], ll);
        stage_B(B + (size_t)k0 * IM + n0, IM, t, Bh, Bl);
        __syncthreads();
        compute_step(lane, wave, Ah, Al, Bh, Bl, acc);
        __syncthreads();
    }
    const int wr = (wave >> 1) * 32, wc = (wave & 1) * 64;
    const int lr = lane & 15, lg = (lane >> 4) * 4;
#pragma unroll
    for (int fi = 0; fi < 2; ++fi)
#pragma unroll
        for (int fj = 0; fj < 4; ++fj)
#pragma unroll
            for (int r = 0; r < 4; ++r) {
                const int ml = wr + fi * 16 + lg + r;
                if (ml < mleft) {
                    const int n = n0 + wc + fj * 16 + lr;
                    Cout[(size_t)(base + m0t + ml) * IM + n] = acc[fi][fj][r];
                }
            }
}

// grouped expert down GEMM + weighted atomic combine into moe[s][n].
// grid: (H/TBN, MAX_TILES)
__global__ __launch_bounds__(256)
void moe_down_kernel(const float* __restrict__ Tin, const float* __restrict__ Wall,
                     const int* __restrict__ counts, const int* __restrict__ offs,
                     const int* __restrict__ tok_list, const float* __restrict__ pw,
                     const int* __restrict__ tile_e, const int* __restrict__ tile_m0,
                     const int* __restrict__ ntiles, float* __restrict__ moe) {
    const int tile = blockIdx.y;
    if (tile >= ntiles[0]) return;
    const int e = tile_e[tile], m0t = tile_m0[tile];
    const int base = offs[e], mleft = counts[e] - m0t;
    const float* B = Wall + (size_t)e * (size_t)IM * H;
    const int n0 = blockIdx.x * TBN;
    __shared__ __align__(16) __bf16 Ah[TBM][BKP], Al[TBM][BKP], Bh[TBN][BKP], Bl[TBN][BKP];
    __shared__ int toks[TBM];
    __shared__ float pws[TBM];
    const int t = threadIdx.x, lane = t & 63, wave = t >> 6;
    if (t < TBM) {
        toks[t] = (t < mleft) ? tok_list[base + m0t + t] : 0;
        pws[t]  = (t < mleft) ? pw[base + m0t + t] : 0.f;
    }
    __syncthreads();
    f32x4 acc[2][4] = {};
    const int ar = t >> 2, kq = (t & 3) * 8;
    for (int k0 = 0; k0 < IM; k0 += TBK) {
        float x[8];
        if (ar < mleft) {
            const float* p = Tin + (size_t)(base + m0t + ar) * IM + k0 + kq;
            float4 va = *(const float4*)p, vb = *(const float4*)(p + 4);
            x[0] = va.x; x[1] = va.y; x[2] = va.z; x[3] = va.w;
            x[4] = vb.x; x[5] = vb.y; x[6] = vb.z; x[7] = vb.w;
        } else {
#pragma unroll
            for (int j = 0; j < 8; ++j) x[j] = 0.f;
        }
        __bf16 hh[8], ll[8];
        cvt8(x, hh, ll);
        store8(&Ah[ar][kq], hh);
        store8(&Al[ar][kq], ll);
        stage_B(B + (size_t)k0 * H + n0, H, t, Bh, Bl);
        __syncthreads();
        compute_step(lane, wave, Ah, Al, Bh, Bl, acc);
        __syncthreads();
    }
    const int wr = (wave >> 1) * 32, wc = (wave & 1) * 64;
    const int lr = lane & 15, lg = (lane >> 4) * 4;
#pragma unroll
    for (int fi = 0; fi < 2; ++fi)
#pragma unroll
        for (int fj = 0; fj < 4; ++fj)
#pragma unroll
            for (int r = 0; r < 4; ++r) {
                const int ml = wr + fi * 16 + lg + r;
                if (ml < mleft) {
                    const int n = n0 + wc + fj * 16 + lr;
                    atomicAdd(&moe[(size_t)toks[ml] * H + n], pws[ml] * acc[fi][fj][r]);
                }
            }
}

// ---------------- legacy f32 GEMM (router only: N=16) ----------------
#define BM 64
#define BN 64
#define BK 16

__global__ __launch_bounds__(256)
void gemm_f32(const float* __restrict__ A, const float* __restrict__ B,
              const float* __restrict__ bias, const float* __restrict__ add,
              float* __restrict__ C, int M, int N, int K) {
    __shared__ float As[BK][BM + 4];
    __shared__ float Bs[BK][BN + 4];
    const int tid = threadIdx.x;
    const int m0 = blockIdx.y * BM, n0 = blockIdx.x * BN;
    const int tx = tid & 15, ty = tid >> 4;
    float c[4][4] = {};
    for (int k0 = 0; k0 < K; k0 += BK) {
        for (int i = tid; i < BM * BK; i += 256) {
            int m = i / BK, kk = i % BK;
            int gm = m0 + m;
            As[kk][m] = (gm < M) ? A[(size_t)gm * K + k0 + kk] : 0.f;
        }
        for (int i = tid; i < BK * BN; i += 256) {
            int kk = i / BN, n = i % BN;
            int gn = n0 + n;
            Bs[kk][n] = (gn < N) ? B[(size_t)(k0 + kk) * N + gn] : 0.f;
        }
        __syncthreads();
#pragma unroll
        for (int kk = 0; kk < BK; ++kk) {
            float a[4], b[4];
#pragma unroll
            for (int i = 0; i < 4; ++i) a[i] = As[kk][ty * 4 + i];
#pragma unroll
            for (int j = 0; j < 4; ++j) b[j] = Bs[kk][tx * 4 + j];
#pragma unroll
            for (int i = 0; i < 4; ++i)
#pragma unroll
                for (int j = 0; j < 4; ++j) c[i][j] += a[i] * b[j];
        }
        __syncthreads();
    }
#pragma unroll
    for (int i = 0; i < 4; ++i) {
        int gm = m0 + ty * 4 + i;
        if (gm >= M) continue;
#pragma unroll
        for (int j = 0; j < 4; ++j) {
            int gn = n0 + tx * 4 + j;
            if (gn >= N) continue;
            float val = c[i][j];
            if (bias) val += bias[gn];
            if (add) val += add[(size_t)gm * N + gn];
            C[(size_t)gm * N + gn] = val;
        }
    }
}

// ---------------- RMSNorm: one block per token ----------------
__global__ __launch_bounds__(256)
void rmsnorm_kernel(const float* __restrict__ x, const float* __restrict__ w,
                    float* __restrict__ o) {
    const int s = blockIdx.x, tid = threadIdx.x;
    __shared__ float red[256];
    const float* xr = x + (size_t)s * H;
    float ss = 0.f;
    for (int d = tid; d < H; d += 256) { float t = xr[d]; ss += t * t; }
    red[tid] = ss; __syncthreads();
    for (int st = 128; st > 0; st >>= 1) {
        if (tid < st) red[tid] += red[tid + st];
        __syncthreads();
    }
    const float r = rsqrtf(red[0] / (float)H + EPS);
    float* orow = o + (size_t)s * H;
    for (int d = tid; d < H; d += 256) orow[d] = xr[d] * r * w[d];
}

// ---------------- RoPE (neox, in place): grid (S, NH), 64 threads ----------
__global__ __launch_bounds__(64)
void rope_kernel(float* __restrict__ x, const int* __restrict__ positions) {
    const int s = blockIdx.x, h = blockIdx.y, t = threadIdx.x;  // t in [0,64)
    const float pos = (float)positions[s];
    const float inv_freq = powf(THETA, -(float)t / 64.0f);
    const float ang = pos * inv_freq;
    float sn, cs;
    sincosf(ang, &sn, &cs);
    const size_t base = (size_t)s * (NH * HD) + (size_t)h * HD;
    const float x1 = x[base + t];
    const float x2 = x[base + t + 64];
    x[base + t]      = x1 * cs - x2 * sn;
    x[base + t + 64] = x2 * cs + x1 * sn;
}

// ---------------- causal attention, naive: block = (query i, head h) -------
__global__ __launch_bounds__(256)
void attn_kernel(const float* __restrict__ q, const float* __restrict__ k,
                 const float* __restrict__ v, float* __restrict__ out) {
    const int i = blockIdx.x, h = blockIdx.y, tid = threadIdx.x;
    __shared__ float qs[HD];
    __shared__ float sc[S];
    __shared__ float red[256];
    const float scale = 0.08838834764831845f;  // 1/sqrt(128)
    for (int d = tid; d < HD; d += 256) qs[d] = q[(size_t)i * (NH * HD) + h * HD + d];
    __syncthreads();
    const int L = i + 1;
    for (int j = tid; j < L; j += 256) {
        const float* kr = k + (size_t)j * (NH * HD) + h * HD;
        float acc = 0.f;
#pragma unroll 16
        for (int d = 0; d < HD; ++d) acc += qs[d] * kr[d];
        sc[j] = acc * scale;
    }
    __syncthreads();
    float mx = -1e30f;
    for (int j = tid; j < L; j += 256) mx = fmaxf(mx, sc[j]);
    red[tid] = mx; __syncthreads();
    for (int st = 128; st > 0; st >>= 1) {
        if (tid < st) red[tid] = fmaxf(red[tid], red[tid + st]);
        __syncthreads();
    }
    mx = red[0]; __syncthreads();
    float sum = 0.f;
    for (int j = tid; j < L; j += 256) { float e = expf(sc[j] - mx); sc[j] = e; sum += e; }
    red[tid] = sum; __syncthreads();
    for (int st = 128; st > 0; st >>= 1) {
        if (tid < st) red[tid] += red[tid + st];
        __syncthreads();
    }
    const float inv = 1.0f / red[0];
    __syncthreads();
    const int d = tid & 127, half = tid >> 7;
    float acc = 0.f;
    for (int j = half; j < L; j += 2) acc += sc[j] * v[(size_t)j * (NH * HD) + h * HD + d];
    red[tid] = acc; __syncthreads();
    if (half == 0)
        out[(size_t)i * (NH * HD) + h * HD + d] = (red[tid] + red[tid + 128]) * inv;
}

// ---------------- silu(g) * u elementwise ----------------
__global__ __launch_bounds__(256)
void silu_mul_kernel(const float* __restrict__ g, const float* __restrict__ u,
                     float* __restrict__ t, size_t n) {
    size_t i = (size_t)blockIdx.x * 256 + threadIdx.x;
    if (i < n) { float x = g[i]; t[i] = x / (1.f + expf(-x)) * u[i]; }
}

// ---------------- sigmoid(h2 . wsg) * shared_row ----------------
__global__ __launch_bounds__(256)
void gate_scale_kernel(const float* __restrict__ h2, const float* __restrict__ wsg,
                       float* __restrict__ shared_out) {
    const int s = blockIdx.x, tid = threadIdx.x;
    __shared__ float red[256];
    float acc = 0.f;
    for (int d = tid; d < H; d += 256) acc += h2[(size_t)s * H + d] * wsg[d];
    red[tid] = acc; __syncthreads();
    for (int st = 128; st > 0; st >>= 1) {
        if (tid < st) red[tid] += red[tid + st];
        __syncthreads();
    }
    const float gate = 1.f / (1.f + expf(-red[0]));
    for (int d = tid; d < H; d += 256) shared_out[(size_t)s * H + d] *= gate;
}

// ---------------- router: softmax + top-4 + renorm, 1 thread per token -----
__global__ __launch_bounds__(256)
void router_top4_kernel(const float* __restrict__ logits, int* __restrict__ tk_ids,
                        float* __restrict__ tk_w) {
    const int s = blockIdx.x * 256 + threadIdx.x;
    if (s >= S) return;
    float l[E];
    float mx = -1e30f;
    for (int e = 0; e < E; ++e) { l[e] = logits[s * E + e]; mx = fmaxf(mx, l[e]); }
    float sum = 0.f;
    for (int e = 0; e < E; ++e) { l[e] = expf(l[e] - mx); sum += l[e]; }
    float wsum = 0.f;
    for (int kk = 0; kk < TOPK; ++kk) {
        int best = 0; float bv = -1e30f;
        for (int e = 0; e < E; ++e) if (l[e] > bv) { bv = l[e]; best = e; }
        tk_ids[s * TOPK + kk] = best;
        float w = bv / sum;
        tk_w[s * TOPK + kk] = w;
        wsum += w;
        l[best] = -1e30f;
    }
    const float inv = 1.f / wsum;
    for (int kk = 0; kk < TOPK; ++kk) tk_w[s * TOPK + kk] *= inv;
}

__global__ void count_pairs_kernel(const int* __restrict__ tk_ids, int* __restrict__ counts) {
    const int s = blockIdx.x * 256 + threadIdx.x;
    if (s >= S) return;
    for (int kk = 0; kk < TOPK; ++kk) atomicAdd(&counts[tk_ids[s * TOPK + kk]], 1);
}

// scan + build (expert, m0) tile table for the grouped MFMA kernels
__global__ void scan_offsets_kernel(const int* __restrict__ counts, int* __restrict__ offs,
                                    int* __restrict__ tile_e, int* __restrict__ tile_m0,
                                    int* __restrict__ ntiles) {
    if (threadIdx.x == 0) {
        int acc = 0, nt = 0;
        for (int e = 0; e < E; ++e) {
            offs[e] = acc;
            const int c = counts[e];
            acc += c;
            for (int m0 = 0; m0 < c; m0 += TBM) { tile_e[nt] = e; tile_m0[nt] = m0; ++nt; }
        }
        ntiles[0] = nt;
    }
}

__global__ void place_pairs_kernel(const int* __restrict__ tk_ids, const float* __restrict__ tk_w,
                                   const int* __restrict__ offs, int* __restrict__ fill,
                                   int* __restrict__ tok_list, float* __restrict__ pw) {
    const int s = blockIdx.x * 256 + threadIdx.x;
    if (s >= S) return;
    for (int kk = 0; kk < TOPK; ++kk) {
        int e = tk_ids[s * TOPK + kk];
        int slot = atomicAdd(&fill[e], 1);
        tok_list[offs[e] + slot] = s;
        pw[offs[e] + slot] = tk_w[s * TOPK + kk];
    }
}

// ---------------- final: out = moe + shared ----------------
__global__ __launch_bounds__(256)
void final_add_kernel(const float* __restrict__ a, const float* __restrict__ b,
                      float* __restrict__ o, size_t n) {
    size_t i = (size_t)blockIdx.x * 256 + threadIdx.x;
    if (i < n) o[i] = a[i] + b[i];
}

// ---------------- host launch ----------------
extern "C" void kernel_launch(void* const* d_in, const int* in_sizes, int n_in,
                              void* d_out, int out_size, void* d_ws, size_t ws_size,
                              hipStream_t stream) {
    const int*   positions = (const int*)  d_in[0];
    const float* hidden    = (const float*)d_in[1];
    const float* ln1_w     = (const float*)d_in[2];
    const float* ln2_w     = (const float*)d_in[3];
    const float* q_w       = (const float*)d_in[4];
    const float* q_b       = (const float*)d_in[5];
    const float* k_w       = (const float*)d_in[6];
    const float* k_b       = (const float*)d_in[7];
    const float* v_w       = (const float*)d_in[8];
    const float* v_b       = (const float*)d_in[9];
    const float* o_w       = (const float*)d_in[10];
    const float* router_w  = (const float*)d_in[11];
    const float* we_gate   = (const float*)d_in[12];
    const float* we_up     = (const float*)d_in[13];
    const float* we_down   = (const float*)d_in[14];
    const float* ws_gate   = (const float*)d_in[15];
    const float* ws_up     = (const float*)d_in[16];
    const float* ws_down   = (const float*)d_in[17];
    const float* wsg       = (const float*)d_in[18];
    float* out = (float*)d_out;

    const size_t SH  = (size_t)S * H;    // 2,097,152
    const size_t SIS = (size_t)S * IS;   // 5,767,168 (== 4096*IM exactly)

    float* f = (float*)d_ws;
    float* h1  = f; f += SH;     // also attention output
    float* qb  = f; f += SH;     // q; later moe accumulator
    float* kb  = f; f += SH;     // k; later shared-expert output
    float* vb  = f; f += SH;
    float* x2  = f; f += SH;
    float* h2  = f; f += SH;
    float* gb  = f; f += SIS;    // shared gate; then expert gate output
    float* ub  = f; f += SIS;    // shared up; then expert up output
    float* logits = f; f += (size_t)S * E;
    float* tkw    = f; f += (size_t)S * TOPK;
    float* pw     = f; f += (size_t)S * TOPK;
    int* ip       = (int*)f;
    int* tk_ids   = ip; ip += S * TOPK;
    int* counts   = ip; ip += E;
    int* offs     = ip; ip += E;
    int* fill     = ip; ip += E;
    int* tok_list = ip; ip += S * TOPK;
    int* tile_e   = ip; ip += 96;
    int* tile_m0  = ip; ip += 96;
    int* ntiles   = ip; ip += 1;

    float* attn_out = h1;
    float* moe      = qb;
    float* shared_o = kb;

    // --- pre-attention ---
    rmsnorm_kernel<<<S, 256, 0, stream>>>(hidden, ln1_w, h1);
    mgemm_qkv_kernel<<<dim3(48, S / TBM), 256, 0, stream>>>(h1, q_w, k_w, v_w,
                                                            q_b, k_b, v_b, qb, kb, vb);
    rope_kernel<<<dim3(S, NH), 64, 0, stream>>>(qb, positions);
    rope_kernel<<<dim3(S, NH), 64, 0, stream>>>(kb, positions);
    attn_kernel<<<dim3(S, NH), 256, 0, stream>>>(qb, kb, vb, attn_out);
    // x2 = attn @ o_w + residual(hidden)
    mgemm_kernel<<<dim3(H / TBN, S / TBM), 256, 0, stream>>>(attn_out, o_w, nullptr, hidden,
                                                             x2, H, NH * HD);
    rmsnorm_kernel<<<S, 256, 0, stream>>>(x2, ln2_w, h2);

    // --- shared expert ---
    mgemm_kernel<<<dim3(IS / TBN, S / TBM), 256, 0, stream>>>(h2, ws_gate, nullptr, nullptr,
                                                              gb, IS, H);
    mgemm_kernel<<<dim3(IS / TBN, S / TBM), 256, 0, stream>>>(h2, ws_up, nullptr, nullptr,
                                                              ub, IS, H);
    silu_mul_kernel<<<(int)(SIS / 256), 256, 0, stream>>>(gb, ub, gb, SIS);
    mgemm_kernel<<<dim3(H / TBN, S / TBM), 256, 0, stream>>>(gb, ws_down, nullptr, nullptr,
                                                             shared_o, H, IS);
    gate_scale_kernel<<<S, 256, 0, stream>>>(h2, wsg, shared_o);

    // --- router ---
    gemm_f32<<<dim3(1, S / BM), 256, 0, stream>>>(h2, router_w, nullptr, nullptr, logits, S, E, H);
    router_top4_kernel<<<S / 256, 256, 0, stream>>>(logits, tk_ids, tkw);
    hipMemsetAsync(counts, 0, sizeof(int) * 3 * E, stream);  // counts, offs, fill
    count_pairs_kernel<<<S / 256, 256, 0, stream>>>(tk_ids, counts);
    scan_offsets_kernel<<<1, 64, 0, stream>>>(counts, offs, tile_e, tile_m0, ntiles);
    place_pairs_kernel<<<S / 256, 256, 0, stream>>>(tk_ids, tkw, offs, fill, tok_list, pw);

    // --- experts (grouped MFMA GEMMs over (expert, token-tile) table) ---
    hipMemsetAsync(moe, 0, SH * sizeof(float), stream);
    moe_gu_kernel<<<dim3(IM / TBN, MAX_TILES), 256, 0, stream>>>(h2, we_gate, counts, offs,
                                                                 tok_list, tile_e, tile_m0,
                                                                 ntiles, gb);
    moe_gu_kernel<<<dim3(IM / TBN, MAX_TILES), 256, 0, stream>>>(h2, we_up, counts, offs,
                                                                 tok_list, tile_e, tile_m0,
                                                                 ntiles, ub);
    silu_mul_kernel<<<(int)(SIS / 256), 256, 0, stream>>>(gb, ub, gb, SIS);
    moe_down_kernel<<<dim3(H / TBN, MAX_TILES), 256, 0, stream>>>(gb, we_down, counts, offs,
                                                                  tok_list, pw, tile_e, tile_m0,
                                                                  ntiles, moe);

    // --- out = moe + shared ---
    final_add_kernel<<<(int)(SH / 256), 256, 0, stream>>>(moe, shared_o, out, SH);
}

// Round 2
// 2064.055 us; speedup vs baseline: 4.4071x; 1.3122x over previous
//
#include <hip/hip_runtime.h>
#include <hip/hip_bf16.h>
#include <math.h>

// ---------------- problem constants ----------------
#define S 1024
#define H 2048
#define NH 16
#define HD 128
#define E 16
#define TOPK 4
#define IM 1408
#define IS 5632
#define EPS 1e-6f
#define THETA 1000000.0f

// =====================================================================
// MFMA bf16x3 GEMM machinery (f32 in/out, split-bf16 emulation)
//   C = A @ B,  A:[M,K] row-major, B:[K,N] row-major
//   A = Ah + Al (bf16 hi/lo), C ~= Ah*Bh + Ah*Bl + Al*Bh  (f32 MFMA accum)
// Tile: 64(M) x 128(N) x 32(K), 256 threads = 4 waves (2x2),
// per-wave 32x64 = 2x4 fragments of v_mfma_f32_16x16x32_bf16.
// =====================================================================
using bf16x8 = __attribute__((ext_vector_type(8))) __bf16;
using f32x4  = __attribute__((ext_vector_type(4))) float;

#define TBM 64
#define TBN 128
#define TBK 32
#define BKP 40            // padded k extent in bf16 elems (80B rows: 16B-aligned, de-power-of-2 banks)
#define MAX_TILES 80      // max sum_e ceil(cnt_e/64) = 4096/64 + 15 = 79

__device__ __forceinline__ void cvt8(const float* x, __bf16* h, __bf16* l) {
#pragma unroll
    for (int j = 0; j < 8; ++j) {
        __bf16 hj = (__bf16)x[j];
        h[j] = hj;
        l[j] = (__bf16)(x[j] - (float)hj);
    }
}

__device__ __forceinline__ void store8(__bf16* dst, const __bf16* v) {
    bf16x8 t;
#pragma unroll
    for (int j = 0; j < 8; ++j) t[j] = v[j];
    *reinterpret_cast<bf16x8*>(dst) = t;
}

// stage A tile (64 rows x 32 k) from dense rows. thread t: row t/4, k-quad t%4.
__device__ __forceinline__ void stage_A(const float* __restrict__ Atile, int lda, int t,
                                        __bf16 (*Ah)[BKP], __bf16 (*Al)[BKP]) {
    const int ar = t >> 2, kq = (t & 3) * 8;
    const float* p = Atile + (size_t)ar * lda + kq;
    float4 va = *(const float4*)p, vb = *(const float4*)(p + 4);
    float x[8] = {va.x, va.y, va.z, va.w, vb.x, vb.y, vb.z, vb.w};
    __bf16 hh[8], ll[8];
    cvt8(x, hh, ll);
    store8(&Ah[ar][kq], hh);
    store8(&Al[ar][kq], ll);
}

// stage B tile (32 k x 128 n) transposed into LDS [n][k].
__device__ __forceinline__ void stage_B(const float* __restrict__ Btile, int ldb, int t,
                                        __bf16 (*Bh)[BKP], __bf16 (*Bl)[BKP]) {
    const int n = (t & 63) * 2;
    const int kb = (t >> 6) * 8;
    const float* p = Btile + (size_t)kb * ldb + n;
    float xa[8], xb[8];
#pragma unroll
    for (int i = 0; i < 8; ++i) {
        float2 v = *(const float2*)(p + (size_t)i * ldb);
        xa[i] = v.x; xb[i] = v.y;
    }
    __bf16 hh[8], ll[8];
    cvt8(xa, hh, ll); store8(&Bh[n][kb], hh); store8(&Bl[n][kb], ll);
    cvt8(xb, hh, ll); store8(&Bh[n + 1][kb], hh); store8(&Bl[n + 1][kb], ll);
}

// one K-step of MFMA work for this thread's wave.
// D: col = lane&15, row = (lane>>4)*4 + reg   [HW-verified m89/m91]
__device__ __forceinline__ void compute_step(int lane, int wave,
        const __bf16 (*Ah)[BKP], const __bf16 (*Al)[BKP],
        const __bf16 (*Bh)[BKP], const __bf16 (*Bl)[BKP],
        f32x4 (&acc)[2][4]) {
    const int wr = (wave >> 1) * 32, wc = (wave & 1) * 64;
    const int lr = lane & 15, lk = (lane >> 4) * 8;
    bf16x8 ah[2], al[2], bh[4], bl[4];
#pragma unroll
    for (int fi = 0; fi < 2; ++fi) {
        ah[fi] = *reinterpret_cast<const bf16x8*>(&Ah[wr + fi * 16 + lr][lk]);
        al[fi] = *reinterpret_cast<const bf16x8*>(&Al[wr + fi * 16 + lr][lk]);
    }
#pragma unroll
    for (int fj = 0; fj < 4; ++fj) {
        bh[fj] = *reinterpret_cast<const bf16x8*>(&Bh[wc + fj * 16 + lr][lk]);
        bl[fj] = *reinterpret_cast<const bf16x8*>(&Bl[wc + fj * 16 + lr][lk]);
    }
#pragma unroll
    for (int fi = 0; fi < 2; ++fi)
#pragma unroll
        for (int fj = 0; fj < 4; ++fj) {
            acc[fi][fj] = __builtin_amdgcn_mfma_f32_16x16x32_bf16(ah[fi], bh[fj], acc[fi][fj], 0, 0, 0);
            acc[fi][fj] = __builtin_amdgcn_mfma_f32_16x16x32_bf16(ah[fi], bl[fj], acc[fi][fj], 0, 0, 0);
            acc[fi][fj] = __builtin_amdgcn_mfma_f32_16x16x32_bf16(al[fi], bh[fj], acc[fi][fj], 0, 0, 0);
        }
}

// dense body shared by mgemm / qkv kernels.
__device__ __forceinline__ void mgemm_body(const float* __restrict__ A, const float* __restrict__ B,
                                           const float* __restrict__ bias, const float* __restrict__ add,
                                           float* __restrict__ C, int N, int K, int m0, int n0) {
    __shared__ __align__(16) __bf16 Ah[TBM][BKP], Al[TBM][BKP], Bh[TBN][BKP], Bl[TBN][BKP];
    const int t = threadIdx.x, lane = t & 63, wave = t >> 6;
    f32x4 acc[2][4] = {};
    for (int k0 = 0; k0 < K; k0 += TBK) {
        stage_A(A + (size_t)m0 * K + k0, K, t, Ah, Al);
        stage_B(B + (size_t)k0 * N + n0, N, t, Bh, Bl);
        __syncthreads();
        compute_step(lane, wave, Ah, Al, Bh, Bl, acc);
        __syncthreads();
    }
    const int wr = (wave >> 1) * 32, wc = (wave & 1) * 64;
    const int lr = lane & 15, lg = (lane >> 4) * 4;
#pragma unroll
    for (int fi = 0; fi < 2; ++fi)
#pragma unroll
        for (int fj = 0; fj < 4; ++fj) {
            const int n = n0 + wc + fj * 16 + lr;
            const float bv = bias ? bias[n] : 0.f;
#pragma unroll
            for (int r = 0; r < 4; ++r) {
                const int m = m0 + wr + fi * 16 + lg + r;
                float val = acc[fi][fj][r] + bv;
                if (add) val += add[(size_t)m * N + n];
                C[(size_t)m * N + n] = val;
            }
        }
}

__global__ __launch_bounds__(256)
void mgemm_kernel(const float* __restrict__ A, const float* __restrict__ B,
                  const float* __restrict__ bias, const float* __restrict__ add,
                  float* __restrict__ C, int N, int K) {
    mgemm_body(A, B, bias, add, C, N, K, blockIdx.y * TBM, blockIdx.x * TBN);
}

// q,k,v fused into one launch: blockIdx.x in [0,48): which = x>>4, n-block = x&15
__global__ __launch_bounds__(256)
void mgemm_qkv_kernel(const float* __restrict__ Ain,
                      const float* __restrict__ qw, const float* __restrict__ kw,
                      const float* __restrict__ vw,
                      const float* __restrict__ qbias, const float* __restrict__ kbias,
                      const float* __restrict__ vbias,
                      float* __restrict__ qo, float* __restrict__ ko, float* __restrict__ vo) {
    const int which = blockIdx.x >> 4;
    const int n0 = (blockIdx.x & 15) * TBN;
    const float* B   = (which == 0) ? qw    : (which == 1) ? kw    : vw;
    const float* bia = (which == 0) ? qbias : (which == 1) ? kbias : vbias;
    float* C         = (which == 0) ? qo    : (which == 1) ? ko    : vo;
    mgemm_body(Ain, B, bia, nullptr, C, H, H, blockIdx.y * TBM, n0);
}

// grouped expert gate/up GEMM: rows gathered from h2 via tok_list.
__global__ __launch_bounds__(256)
void moe_gu_kernel(const float* __restrict__ h2, const float* __restrict__ Wall,
                   const int* __restrict__ counts, const int* __restrict__ offs,
                   const int* __restrict__ tok_list, const int* __restrict__ tile_e,
                   const int* __restrict__ tile_m0, const int* __restrict__ ntiles,
                   float* __restrict__ Cout) {
    const int tile = blockIdx.y;
    if (tile >= ntiles[0]) return;
    const int e = tile_e[tile], m0t = tile_m0[tile];
    const int base = offs[e], mleft = counts[e] - m0t;
    const float* B = Wall + (size_t)e * (size_t)H * IM;
    const int n0 = blockIdx.x * TBN;
    __shared__ __align__(16) __bf16 Ah[TBM][BKP], Al[TBM][BKP], Bh[TBN][BKP], Bl[TBN][BKP];
    __shared__ int toks[TBM];
    const int t = threadIdx.x, lane = t & 63, wave = t >> 6;
    if (t < TBM) toks[t] = (t < mleft) ? tok_list[base + m0t + t] : 0;
    __syncthreads();
    f32x4 acc[2][4] = {};
    const int ar = t >> 2, kq = (t & 3) * 8;
    for (int k0 = 0; k0 < H; k0 += TBK) {
        float x[8];
        if (ar < mleft) {
            const float* p = h2 + (size_t)toks[ar] * H + k0 + kq;
            float4 va = *(const float4*)p, vb = *(const float4*)(p + 4);
            x[0] = va.x; x[1] = va.y; x[2] = va.z; x[3] = va.w;
            x[4] = vb.x; x[5] = vb.y; x[6] = vb.z; x[7] = vb.w;
        } else {
#pragma unroll
            for (int j = 0; j < 8; ++j) x[j] = 0.f;
        }
        __bf16 hh[8], ll[8];
        cvt8(x, hh, ll);
        store8(&Ah[ar][kq], hh);
        store8(&Al[ar][kq], ll);
        stage_B(B + (size_t)k0 * IM + n0, IM, t, Bh, Bl);
        __syncthreads();
        compute_step(lane, wave, Ah, Al, Bh, Bl, acc);
        __syncthreads();
    }
    const int wr = (wave >> 1) * 32, wc = (wave & 1) * 64;
    const int lr = lane & 15, lg = (lane >> 4) * 4;
#pragma unroll
    for (int fi = 0; fi < 2; ++fi)
#pragma unroll
        for (int fj = 0; fj < 4; ++fj)
#pragma unroll
            for (int r = 0; r < 4; ++r) {
                const int ml = wr + fi * 16 + lg + r;
                if (ml < mleft) {
                    const int n = n0 + wc + fj * 16 + lr;
                    Cout[(size_t)(base + m0t + ml) * IM + n] = acc[fi][fj][r];
                }
            }
}

// grouped expert down GEMM + weighted atomic combine into moe[s][n].
__global__ __launch_bounds__(256)
void moe_down_kernel(const float* __restrict__ Tin, const float* __restrict__ Wall,
                     const int* __restrict__ counts, const int* __restrict__ offs,
                     const int* __restrict__ tok_list, const float* __restrict__ pw,
                     const int* __restrict__ tile_e, const int* __restrict__ tile_m0,
                     const int* __restrict__ ntiles, float* __restrict__ moe) {
    const int tile = blockIdx.y;
    if (tile >= ntiles[0]) return;
    const int e = tile_e[tile], m0t = tile_m0[tile];
    const int base = offs[e], mleft = counts[e] - m0t;
    const float* B = Wall + (size_t)e * (size_t)IM * H;
    const int n0 = blockIdx.x * TBN;
    __shared__ __align__(16) __bf16 Ah[TBM][BKP], Al[TBM][BKP], Bh[TBN][BKP], Bl[TBN][BKP];
    __shared__ int toks[TBM];
    __shared__ float pws[TBM];
    const int t = threadIdx.x, lane = t & 63, wave = t >> 6;
    if (t < TBM) {
        toks[t] = (t < mleft) ? tok_list[base + m0t + t] : 0;
        pws[t]  = (t < mleft) ? pw[base + m0t + t] : 0.f;
    }
    __syncthreads();
    f32x4 acc[2][4] = {};
    const int ar = t >> 2, kq = (t & 3) * 8;
    for (int k0 = 0; k0 < IM; k0 += TBK) {
        float x[8];
        if (ar < mleft) {
            const float* p = Tin + (size_t)(base + m0t + ar) * IM + k0 + kq;
            float4 va = *(const float4*)p, vb = *(const float4*)(p + 4);
            x[0] = va.x; x[1] = va.y; x[2] = va.z; x[3] = va.w;
            x[4] = vb.x; x[5] = vb.y; x[6] = vb.z; x[7] = vb.w;
        } else {
#pragma unroll
            for (int j = 0; j < 8; ++j) x[j] = 0.f;
        }
        __bf16 hh[8], ll[8];
        cvt8(x, hh, ll);
        store8(&Ah[ar][kq], hh);
        store8(&Al[ar][kq], ll);
        stage_B(B + (size_t)k0 * H + n0, H, t, Bh, Bl);
        __syncthreads();
        compute_step(lane, wave, Ah, Al, Bh, Bl, acc);
        __syncthreads();
    }
    const int wr = (wave >> 1) * 32, wc = (wave & 1) * 64;
    const int lr = lane & 15, lg = (lane >> 4) * 4;
#pragma unroll
    for (int fi = 0; fi < 2; ++fi)
#pragma unroll
        for (int fj = 0; fj < 4; ++fj)
#pragma unroll
            for (int r = 0; r < 4; ++r) {
                const int ml = wr + fi * 16 + lg + r;
                if (ml < mleft) {
                    const int n = n0 + wc + fj * 16 + lr;
                    atomicAdd(&moe[(size_t)toks[ml] * H + n], pws[ml] * acc[fi][fj][r]);
                }
            }
}

// =====================================================================
// Flash attention (causal), MFMA split-bf16.
// Block = (q-tile of 64 rows, head). 4 waves x 16 q-rows each.
// K/V tiles of 32 rows staged in LDS per step; online softmax.
// =====================================================================
#define QBLK 64
#define KVBLK 32
#define KP 136    // K row pad (128 + 8) bf16: 272B rows = 17x16B (odd unit stride)
#define VP 40     // Vt/P row pad (32 + 8) bf16: 80B rows

__global__ __launch_bounds__(256)
void flash_attn_kernel(const float* __restrict__ q, const float* __restrict__ k,
                       const float* __restrict__ v, float* __restrict__ out) {
    const int qt = blockIdx.x, h = blockIdx.y;
    const int q0 = qt * QBLK;
    const int t = threadIdx.x, lane = t & 63, w = t >> 6;
    const int lr = lane & 15, lg = lane >> 4;         // lg in [0,4)
    const float scale = 0.08838834764831845f;          // 1/sqrt(128)

    __shared__ __align__(16) __bf16 Kh[KVBLK][KP], Kl[KVBLK][KP];
    __shared__ __align__(16) __bf16 Vh[HD][VP], Vl[HD][VP];      // transposed: [d][k]
    __shared__ __align__(16) __bf16 Ph[4][16][VP], Pl[4][16][VP]; // per-wave P

    // ---- Q fragments in registers (A-operand layout), softmax scale folded ----
    bf16x8 qh[4], ql[4];
    {
        const int qrow = q0 + w * 16 + lr;
        const float* qp = q + (size_t)qrow * (NH * HD) + h * HD + lg * 8;
#pragma unroll
        for (int kf = 0; kf < 4; ++kf) {
            float4 a = *(const float4*)(qp + kf * 32);
            float4 b = *(const float4*)(qp + kf * 32 + 4);
            float x[8] = {a.x, a.y, a.z, a.w, b.x, b.y, b.z, b.w};
            bf16x8 hh, ll;
#pragma unroll
            for (int j = 0; j < 8; ++j) {
                float xs = x[j] * scale;
                __bf16 hj = (__bf16)xs;
                hh[j] = hj;
                ll[j] = (__bf16)(xs - (float)hj);
            }
            qh[kf] = hh; ql[kf] = ll;
        }
    }

    f32x4 o_acc[8] = {};
    float m_run[4] = {-1e30f, -1e30f, -1e30f, -1e30f};
    float l_run[4] = {0.f, 0.f, 0.f, 0.f};

    const int nsteps = (q0 + QBLK) / KVBLK;   // 2*qt + 2
    const int srow = t >> 3, sd0 = (t & 7) * 16;   // staging: 8 threads/row, 16 floats each

    for (int kt = 0; kt < nsteps; ++kt) {
        const int kk0 = kt * KVBLK;
        // ---- stage K tile [32][128] and V tile transposed [128][32] ----
        {
            const float* kp = k + (size_t)(kk0 + srow) * (NH * HD) + h * HD + sd0;
            float x[16];
#pragma unroll
            for (int i = 0; i < 4; ++i) {
                float4 vv = *(const float4*)(kp + i * 4);
                x[i * 4 + 0] = vv.x; x[i * 4 + 1] = vv.y; x[i * 4 + 2] = vv.z; x[i * 4 + 3] = vv.w;
            }
            __bf16 hh[16], ll[16];
#pragma unroll
            for (int j = 0; j < 16; ++j) {
                __bf16 hj = (__bf16)x[j];
                hh[j] = hj; ll[j] = (__bf16)(x[j] - (float)hj);
            }
            store8(&Kh[srow][sd0], hh);     store8(&Kh[srow][sd0 + 8], hh + 8);
            store8(&Kl[srow][sd0], ll);     store8(&Kl[srow][sd0 + 8], ll + 8);

            const float* vp = v + (size_t)(kk0 + srow) * (NH * HD) + h * HD + sd0;
#pragma unroll
            for (int i = 0; i < 4; ++i) {
                float4 vv = *(const float4*)(vp + i * 4);
                x[i * 4 + 0] = vv.x; x[i * 4 + 1] = vv.y; x[i * 4 + 2] = vv.z; x[i * 4 + 3] = vv.w;
            }
#pragma unroll
            for (int j = 0; j < 16; ++j) {
                __bf16 hj = (__bf16)x[j];
                Vh[sd0 + j][srow] = hj;
                Vl[sd0 + j][srow] = (__bf16)(x[j] - (float)hj);
            }
        }
        __syncthreads();

        // ---- QK^T: 16 q-rows x 32 k-cols per wave = 2 fragments ----
        f32x4 sc[2] = {};
#pragma unroll
        for (int f = 0; f < 2; ++f)
#pragma unroll
            for (int ds = 0; ds < 4; ++ds) {
                bf16x8 bh = *reinterpret_cast<const bf16x8*>(&Kh[f * 16 + lr][ds * 32 + lg * 8]);
                bf16x8 bl = *reinterpret_cast<const bf16x8*>(&Kl[f * 16 + lr][ds * 32 + lg * 8]);
                sc[f] = __builtin_amdgcn_mfma_f32_16x16x32_bf16(qh[ds], bh, sc[f], 0, 0, 0);
                sc[f] = __builtin_amdgcn_mfma_f32_16x16x32_bf16(qh[ds], bl, sc[f], 0, 0, 0);
                sc[f] = __builtin_amdgcn_mfma_f32_16x16x32_bf16(ql[ds], bh, sc[f], 0, 0, 0);
            }

        // ---- causal mask (only diagonal tiles) ----
        if (kk0 >= q0) {
#pragma unroll
            for (int f = 0; f < 2; ++f)
#pragma unroll
                for (int r = 0; r < 4; ++r) {
                    const int kcol = kk0 + f * 16 + lr;
                    const int qrow = q0 + w * 16 + lg * 4 + r;
                    if (kcol > qrow) sc[f][r] = -1e30f;
                }
        }

        // ---- online softmax (row spread across 16 lanes; lane owns 4 rows) ----
        float tmax[4], corr[4], psum[4];
#pragma unroll
        for (int r = 0; r < 4; ++r) tmax[r] = fmaxf(sc[0][r], sc[1][r]);
#pragma unroll
        for (int x = 1; x < 16; x <<= 1)
#pragma unroll
            for (int r = 0; r < 4; ++r) tmax[r] = fmaxf(tmax[r], __shfl_xor(tmax[r], x));
#pragma unroll
        for (int r = 0; r < 4; ++r) {
            float mn = fmaxf(m_run[r], tmax[r]);
            corr[r] = expf(m_run[r] - mn);
            m_run[r] = mn;
            psum[r] = 0.f;
        }
#pragma unroll
        for (int f = 0; f < 2; ++f)
#pragma unroll
            for (int r = 0; r < 4; ++r) {
                float p = expf(sc[f][r] - m_run[r]);
                sc[f][r] = p;
                psum[r] += p;
            }
#pragma unroll
        for (int x = 1; x < 16; x <<= 1)
#pragma unroll
            for (int r = 0; r < 4; ++r) psum[r] += __shfl_xor(psum[r], x);
#pragma unroll
        for (int r = 0; r < 4; ++r) l_run[r] = l_run[r] * corr[r] + psum[r];
#pragma unroll
        for (int fj = 0; fj < 8; ++fj)
#pragma unroll
            for (int r = 0; r < 4; ++r) o_acc[fj][r] *= corr[r];

        // ---- P -> bf16 split, through per-wave LDS (D-layout -> A-layout) ----
#pragma unroll
        for (int f = 0; f < 2; ++f)
#pragma unroll
            for (int r = 0; r < 4; ++r) {
                float p = sc[f][r];
                __bf16 hj = (__bf16)p;
                Ph[w][lg * 4 + r][f * 16 + lr] = hj;
                Pl[w][lg * 4 + r][f * 16 + lr] = (__bf16)(p - (float)hj);
            }
        bf16x8 pa_h = *reinterpret_cast<const bf16x8*>(&Ph[w][lr][lg * 8]);
        bf16x8 pa_l = *reinterpret_cast<const bf16x8*>(&Pl[w][lr][lg * 8]);

        // ---- PV: O[16 x 128] += P[16 x 32] @ V[32 x 128] ----
#pragma unroll
        for (int fj = 0; fj < 8; ++fj) {
            bf16x8 bh = *reinterpret_cast<const bf16x8*>(&Vh[fj * 16 + lr][lg * 8]);
            bf16x8 bl = *reinterpret_cast<const bf16x8*>(&Vl[fj * 16 + lr][lg * 8]);
            o_acc[fj] = __builtin_amdgcn_mfma_f32_16x16x32_bf16(pa_h, bh, o_acc[fj], 0, 0, 0);
            o_acc[fj] = __builtin_amdgcn_mfma_f32_16x16x32_bf16(pa_h, bl, o_acc[fj], 0, 0, 0);
            o_acc[fj] = __builtin_amdgcn_mfma_f32_16x16x32_bf16(pa_l, bh, o_acc[fj], 0, 0, 0);
        }
        __syncthreads();
    }

    // ---- epilogue: normalize and store ----
    float inv[4];
#pragma unroll
    for (int r = 0; r < 4; ++r) inv[r] = 1.0f / l_run[r];
#pragma unroll
    for (int fj = 0; fj < 8; ++fj)
#pragma unroll
        for (int r = 0; r < 4; ++r) {
            const int qrow = q0 + w * 16 + lg * 4 + r;
            out[(size_t)qrow * (NH * HD) + h * HD + fj * 16 + lr] = o_acc[fj][r] * inv[r];
        }
}

// ---------------- legacy f32 GEMM (router only: N=16) ----------------
#define BM 64
#define BN 64
#define BK 16

__global__ __launch_bounds__(256)
void gemm_f32(const float* __restrict__ A, const float* __restrict__ B,
              const float* __restrict__ bias, const float* __restrict__ add,
              float* __restrict__ C, int M, int N, int K) {
    __shared__ float As[BK][BM + 4];
    __shared__ float Bs[BK][BN + 4];
    const int tid = threadIdx.x;
    const int m0 = blockIdx.y * BM, n0 = blockIdx.x * BN;
    const int tx = tid & 15, ty = tid >> 4;
    float c[4][4] = {};
    for (int k0 = 0; k0 < K; k0 += BK) {
        for (int i = tid; i < BM * BK; i += 256) {
            int m = i / BK, kk = i % BK;
            int gm = m0 + m;
            As[kk][m] = (gm < M) ? A[(size_t)gm * K + k0 + kk] : 0.f;
        }
        for (int i = tid; i < BK * BN; i += 256) {
            int kk = i / BN, n = i % BN;
            int gn = n0 + n;
            Bs[kk][n] = (gn < N) ? B[(size_t)(k0 + kk) * N + gn] : 0.f;
        }
        __syncthreads();
#pragma unroll
        for (int kk = 0; kk < BK; ++kk) {
            float a[4], b[4];
#pragma unroll
            for (int i = 0; i < 4; ++i) a[i] = As[kk][ty * 4 + i];
#pragma unroll
            for (int j = 0; j < 4; ++j) b[j] = Bs[kk][tx * 4 + j];
#pragma unroll
            for (int i = 0; i < 4; ++i)
#pragma unroll
                for (int j = 0; j < 4; ++j) c[i][j] += a[i] * b[j];
        }
        __syncthreads();
    }
#pragma unroll
    for (int i = 0; i < 4; ++i) {
        int gm = m0 + ty * 4 + i;
        if (gm >= M) continue;
#pragma unroll
        for (int j = 0; j < 4; ++j) {
            int gn = n0 + tx * 4 + j;
            if (gn >= N) continue;
            float val = c[i][j];
            if (bias) val += bias[gn];
            if (add) val += add[(size_t)gm * N + gn];
            C[(size_t)gm * N + gn] = val;
        }
    }
}

// ---------------- RMSNorm: one block per token ----------------
__global__ __launch_bounds__(256)
void rmsnorm_kernel(const float* __restrict__ x, const float* __restrict__ w,
                    float* __restrict__ o) {
    const int s = blockIdx.x, tid = threadIdx.x;
    __shared__ float red[256];
    const float* xr = x + (size_t)s * H;
    float ss = 0.f;
    for (int d = tid; d < H; d += 256) { float t = xr[d]; ss += t * t; }
    red[tid] = ss; __syncthreads();
    for (int st = 128; st > 0; st >>= 1) {
        if (tid < st) red[tid] += red[tid + st];
        __syncthreads();
    }
    const float r = rsqrtf(red[0] / (float)H + EPS);
    float* orow = o + (size_t)s * H;
    for (int d = tid; d < H; d += 256) orow[d] = xr[d] * r * w[d];
}

// ---------------- RoPE (neox, in place): grid (S, NH), 64 threads ----------
__global__ __launch_bounds__(64)
void rope_kernel(float* __restrict__ x, const int* __restrict__ positions) {
    const int s = blockIdx.x, h = blockIdx.y, t = threadIdx.x;  // t in [0,64)
    const float pos = (float)positions[s];
    const float inv_freq = powf(THETA, -(float)t / 64.0f);
    const float ang = pos * inv_freq;
    float sn, cs;
    sincosf(ang, &sn, &cs);
    const size_t base = (size_t)s * (NH * HD) + (size_t)h * HD;
    const float x1 = x[base + t];
    const float x2 = x[base + t + 64];
    x[base + t]      = x1 * cs - x2 * sn;
    x[base + t + 64] = x2 * cs + x1 * sn;
}

// ---------------- silu(g) * u elementwise ----------------
__global__ __launch_bounds__(256)
void silu_mul_kernel(const float* __restrict__ g, const float* __restrict__ u,
                     float* __restrict__ t, size_t n) {
    size_t i = (size_t)blockIdx.x * 256 + threadIdx.x;
    if (i < n) { float x = g[i]; t[i] = x / (1.f + expf(-x)) * u[i]; }
}

// ---------------- sigmoid(h2 . wsg) * shared_row ----------------
__global__ __launch_bounds__(256)
void gate_scale_kernel(const float* __restrict__ h2, const float* __restrict__ wsg,
                       float* __restrict__ shared_out) {
    const int s = blockIdx.x, tid = threadIdx.x;
    __shared__ float red[256];
    float acc = 0.f;
    for (int d = tid; d < H; d += 256) acc += h2[(size_t)s * H + d] * wsg[d];
    red[tid] = acc; __syncthreads();
    for (int st = 128; st > 0; st >>= 1) {
        if (tid < st) red[tid] += red[tid + st];
        __syncthreads();
    }
    const float gate = 1.f / (1.f + expf(-red[0]));
    for (int d = tid; d < H; d += 256) shared_out[(size_t)s * H + d] *= gate;
}

// ---------------- router: softmax + top-4 + renorm, 1 thread per token -----
__global__ __launch_bounds__(256)
void router_top4_kernel(const float* __restrict__ logits, int* __restrict__ tk_ids,
                        float* __restrict__ tk_w) {
    const int s = blockIdx.x * 256 + threadIdx.x;
    if (s >= S) return;
    float l[E];
    float mx = -1e30f;
    for (int e = 0; e < E; ++e) { l[e] = logits[s * E + e]; mx = fmaxf(mx, l[e]); }
    float sum = 0.f;
    for (int e = 0; e < E; ++e) { l[e] = expf(l[e] - mx); sum += l[e]; }
    float wsum = 0.f;
    for (int kk = 0; kk < TOPK; ++kk) {
        int best = 0; float bv = -1e30f;
        for (int e = 0; e < E; ++e) if (l[e] > bv) { bv = l[e]; best = e; }
        tk_ids[s * TOPK + kk] = best;
        float w = bv / sum;
        tk_w[s * TOPK + kk] = w;
        wsum += w;
        l[best] = -1e30f;
    }
    const float inv = 1.f / wsum;
    for (int kk = 0; kk < TOPK; ++kk) tk_w[s * TOPK + kk] *= inv;
}

__global__ void count_pairs_kernel(const int* __restrict__ tk_ids, int* __restrict__ counts) {
    const int s = blockIdx.x * 256 + threadIdx.x;
    if (s >= S) return;
    for (int kk = 0; kk < TOPK; ++kk) atomicAdd(&counts[tk_ids[s * TOPK + kk]], 1);
}

// scan + build (expert, m0) tile table for the grouped MFMA kernels
__global__ void scan_offsets_kernel(const int* __restrict__ counts, int* __restrict__ offs,
                                    int* __restrict__ tile_e, int* __restrict__ tile_m0,
                                    int* __restrict__ ntiles) {
    if (threadIdx.x == 0) {
        int acc = 0, nt = 0;
        for (int e = 0; e < E; ++e) {
            offs[e] = acc;
            const int c = counts[e];
            acc += c;
            for (int m0 = 0; m0 < c; m0 += TBM) { tile_e[nt] = e; tile_m0[nt] = m0; ++nt; }
        }
        ntiles[0] = nt;
    }
}

__global__ void place_pairs_kernel(const int* __restrict__ tk_ids, const float* __restrict__ tk_w,
                                   const int* __restrict__ offs, int* __restrict__ fill,
                                   int* __restrict__ tok_list, float* __restrict__ pw) {
    const int s = blockIdx.x * 256 + threadIdx.x;
    if (s >= S) return;
    for (int kk = 0; kk < TOPK; ++kk) {
        int e = tk_ids[s * TOPK + kk];
        int slot = atomicAdd(&fill[e], 1);
        tok_list[offs[e] + slot] = s;
        pw[offs[e] + slot] = tk_w[s * TOPK + kk];
    }
}

// ---------------- final: out = moe + shared ----------------
__global__ __launch_bounds__(256)
void final_add_kernel(const float* __restrict__ a, const float* __restrict__ b,
                      float* __restrict__ o, size_t n) {
    size_t i = (size_t)blockIdx.x * 256 + threadIdx.x;
    if (i < n) o[i] = a[i] + b[i];
}

// ---------------- host launch ----------------
extern "C" void kernel_launch(void* const* d_in, const int* in_sizes, int n_in,
                              void* d_out, int out_size, void* d_ws, size_t ws_size,
                              hipStream_t stream) {
    const int*   positions = (const int*)  d_in[0];
    const float* hidden    = (const float*)d_in[1];
    const float* ln1_w     = (const float*)d_in[2];
    const float* ln2_w     = (const float*)d_in[3];
    const float* q_w       = (const float*)d_in[4];
    const float* q_b       = (const float*)d_in[5];
    const float* k_w       = (const float*)d_in[6];
    const float* k_b       = (const float*)d_in[7];
    const float* v_w       = (const float*)d_in[8];
    const float* v_b       = (const float*)d_in[9];
    const float* o_w       = (const float*)d_in[10];
    const float* router_w  = (const float*)d_in[11];
    const float* we_gate   = (const float*)d_in[12];
    const float* we_up     = (const float*)d_in[13];
    const float* we_down   = (const float*)d_in[14];
    const float* ws_gate   = (const float*)d_in[15];
    const float* ws_up     = (const float*)d_in[16];
    const float* ws_down   = (const float*)d_in[17];
    const float* wsg       = (const float*)d_in[18];
    float* out = (float*)d_out;

    const size_t SH  = (size_t)S * H;    // 2,097,152
    const size_t SIS = (size_t)S * IS;   // 5,767,168 (== 4096*IM exactly)

    float* f = (float*)d_ws;
    float* h1  = f; f += SH;     // also attention output
    float* qb  = f; f += SH;     // q; later moe accumulator
    float* kb  = f; f += SH;     // k; later shared-expert output
    float* vb  = f; f += SH;
    float* x2  = f; f += SH;
    float* h2  = f; f += SH;
    float* gb  = f; f += SIS;    // shared gate; then expert gate output
    float* ub  = f; f += SIS;    // shared up; then expert up output
    float* logits = f; f += (size_t)S * E;
    float* tkw    = f; f += (size_t)S * TOPK;
    float* pw     = f; f += (size_t)S * TOPK;
    int* ip       = (int*)f;
    int* tk_ids   = ip; ip += S * TOPK;
    int* counts   = ip; ip += E;
    int* offs     = ip; ip += E;
    int* fill     = ip; ip += E;
    int* tok_list = ip; ip += S * TOPK;
    int* tile_e   = ip; ip += 96;
    int* tile_m0  = ip; ip += 96;
    int* ntiles   = ip; ip += 1;

    float* attn_out = h1;
    float* moe      = qb;
    float* shared_o = kb;

    // --- pre-attention ---
    rmsnorm_kernel<<<S, 256, 0, stream>>>(hidden, ln1_w, h1);
    mgemm_qkv_kernel<<<dim3(48, S / TBM), 256, 0, stream>>>(h1, q_w, k_w, v_w,
                                                            q_b, k_b, v_b, qb, kb, vb);
    rope_kernel<<<dim3(S, NH), 64, 0, stream>>>(qb, positions);
    rope_kernel<<<dim3(S, NH), 64, 0, stream>>>(kb, positions);
    flash_attn_kernel<<<dim3(S / QBLK, NH), 256, 0, stream>>>(qb, kb, vb, attn_out);
    // x2 = attn @ o_w + residual(hidden)
    mgemm_kernel<<<dim3(H / TBN, S / TBM), 256, 0, stream>>>(attn_out, o_w, nullptr, hidden,
                                                             x2, H, NH * HD);
    rmsnorm_kernel<<<S, 256, 0, stream>>>(x2, ln2_w, h2);

    // --- shared expert ---
    mgemm_kernel<<<dim3(IS / TBN, S / TBM), 256, 0, stream>>>(h2, ws_gate, nullptr, nullptr,
                                                              gb, IS, H);
    mgemm_kernel<<<dim3(IS / TBN, S / TBM), 256, 0, stream>>>(h2, ws_up, nullptr, nullptr,
                                                              ub, IS, H);
    silu_mul_kernel<<<(int)(SIS / 256), 256, 0, stream>>>(gb, ub, gb, SIS);
    mgemm_kernel<<<dim3(H / TBN, S / TBM), 256, 0, stream>>>(gb, ws_down, nullptr, nullptr,
                                                             shared_o, H, IS);
    gate_scale_kernel<<<S, 256, 0, stream>>>(h2, wsg, shared_o);

    // --- router ---
    gemm_f32<<<dim3(1, S / BM), 256, 0, stream>>>(h2, router_w, nullptr, nullptr, logits, S, E, H);
    router_top4_kernel<<<S / 256, 256, 0, stream>>>(logits, tk_ids, tkw);
    hipMemsetAsync(counts, 0, sizeof(int) * 3 * E, stream);  // counts, offs, fill
    count_pairs_kernel<<<S / 256, 256, 0, stream>>>(tk_ids, counts);
    scan_offsets_kernel<<<1, 64, 0, stream>>>(counts, offs, tile_e, tile_m0, ntiles);
    place_pairs_kernel<<<S / 256, 256, 0, stream>>>(tk_ids, tkw, offs, fill, tok_list, pw);

    // --- experts (grouped MFMA GEMMs over (expert, token-tile) table) ---
    hipMemsetAsync(moe, 0, SH * sizeof(float), stream);
    moe_gu_kernel<<<dim3(IM / TBN, MAX_TILES), 256, 0, stream>>>(h2, we_gate, counts, offs,
                                                                 tok_list, tile_e, tile_m0,
                                                                 ntiles, gb);
    moe_gu_kernel<<<dim3(IM / TBN, MAX_TILES), 256, 0, stream>>>(h2, we_up, counts, offs,
                                                                 tok_list, tile_e, tile_m0,
                                                                 ntiles, ub);
    silu_mul_kernel<<<(int)(SIS / 256), 256, 0, stream>>>(gb, ub, gb, SIS);
    moe_down_kernel<<<dim3(H / TBN, MAX_TILES), 256, 0, stream>>>(gb, we_down, counts, offs,
                                                                  tok_list, pw, tile_e, tile_m0,
                                                                  ntiles, moe);

    // --- out = moe + shared ---
    final_add_kernel<<<(int)(SH / 256), 256, 0, stream>>>(moe, shared_o, out, SH);
}